// Round 13
// baseline (574.775 us; speedup 1.0000x reference)
//
#include <hip/hip_runtime.h>
#include <math.h>

#define B_ROWS 4096
#define NSTR 4
#define C_DIM 4096
#define NC 16384      // NSTR*C_DIM
#define NC4 4096      // NC/4 (float4 per batch row)
#define C4 1024       // C_DIM/4 (float4 per stream)

// async global->LDS DMA, 16B per lane. LDS dest must be wave-uniform base;
// lane l writes base + l*16. Global src is per-lane.
#define ASYNC_COPY16(g, l)                                                     \
    __builtin_amdgcn_global_load_lds(                                         \
        (const __attribute__((address_space(1))) void*)(g),                   \
        (__attribute__((address_space(3))) void*)(l), 16, 0, 0)

#define DOT4(A, P, XV) { float _a = (A);                                       \
    _a = fmaf((XV).x, (P).x, _a); _a = fmaf((XV).y, (P).y, _a);                \
    _a = fmaf((XV).z, (P).z, _a); _a = fmaf((XV).w, (P).w, _a); (A) = _a; }

// ---------------------------------------------------------------------------
// Kernel 1: projections. Grid = (B_ROWS/8) x 2 K-halves -> 1024 blocks of
// 256 threads (4 waves). Block = 8 batch rows x one K-half (2048 float4).
// Wave w owns phi rows 6w..6w+5 and DMA-stages x rows 2w,2w+1.
//
// R13 SCHEDULE (R12 + phi register-prefetch, distance 1, pA/pB parity):
//   body(c): [s_waitcnt vmcnt(2): in-order counter forces phi(c) x6 AND
//             dma(c) retired; leaves dma(c+1) x2 in flight]
//            [raw s_barrier - no vmcnt(0) drain]
//            [issue phi(c+1) -> PN  (consumed NEXT body)]
//            [issue dma(c+2) -> buf bf]
//            [consume chunk c from LDS + PC registers: ZERO vmem waits]
// phi latency (L2 ~200cy / L3 ~400cy) now covered by a full consume phase.
// phi bases are wave-uniform -> SGPR saddr loads, pB costs only ~24 VGPR.
// 3 LDS buffers; buf bf holds chunk c-1, consumed by all waves before this
// body's barrier -> WAR-safe. LDS 24KB -> 4 blocks/CU, grid fully resident.
// ---------------------------------------------------------------------------
__global__ __launch_bounds__(256, 4) void proj_kernel(
    const float* __restrict__ x,
    const float* __restrict__ phi_pre,
    const float* __restrict__ phi_post,
    const float* __restrict__ phi_res,
    float* __restrict__ dots_part)   // [2][B_ROWS][25]
{
    const float4* __restrict__ x4    = reinterpret_cast<const float4*>(x);
    const float4* __restrict__ pre4  = reinterpret_cast<const float4*>(phi_pre);
    const float4* __restrict__ post4 = reinterpret_cast<const float4*>(phi_post);
    const float4* __restrict__ res4  = reinterpret_cast<const float4*>(phi_res);

    const int bid  = blockIdx.x;
    const int kb   = bid & 1;            // K-half
    const int b0   = (bid >> 1) * 8;     // first batch row
    const int wave = threadIdx.x >> 6;   // 0..3
    const int lane = threadIdx.x & 63;
    const int wv   = __builtin_amdgcn_readfirstlane(wave);
    const int wr0  = 2 * wv;             // this wave's own rows (ssq)
    const int wr1  = 2 * wv + 1;

    __shared__ float4 xs[3][8][64];      // [buf][row][float4] = 24 KB
    __shared__ float  red[4][8][6];      // [wave][row][j]
    __shared__ float  redss[8];          // ssq per row

    const int kbase = kb * 2048;

    // x staging pointers; after prologue they point at chunk 2 (next DMA tgt)
    const float4* srcA = x4 + (size_t)(b0 + 2 * wave)     * NC4 + kbase + lane;
    const float4* srcB = x4 + (size_t)(b0 + 2 * wave + 1) * NC4 + kbase + lane;

    // wave's 6 phi row pointers (wave-uniform base + lane -> SGPR saddr form)
    const int row0 = wv * 6;
    auto rowbase = [&](int row) -> const float4* {
        if (row < 4)  return pre4  + (size_t)row * NC4;
        if (row < 8)  return post4 + (size_t)(row - 4) * NC4;
        return res4 + (size_t)(row - 8) * NC4;
    };
    const float4* pb0 = rowbase(row0 + 0) + kbase + lane;
    const float4* pb1 = rowbase(row0 + 1) + kbase + lane;
    const float4* pb2 = rowbase(row0 + 2) + kbase + lane;
    const float4* pb3 = rowbase(row0 + 3) + kbase + lane;
    const float4* pb4 = rowbase(row0 + 4) + kbase + lane;
    const float4* pb5 = rowbase(row0 + 5) + kbase + lane;

    float acc[8][6];
#pragma unroll
    for (int r = 0; r < 8; ++r)
#pragma unroll
        for (int j = 0; j < 6; ++j) acc[r][j] = 0.f;
    float ssq0 = 0.f, ssq1 = 0.f;

    float4 pA[6], pB[6];

    // ---- prologue ----
    // DMA chunk 0 -> buf0, chunk 1 -> buf1
    ASYNC_COPY16(srcA,      &xs[0][2 * wave][0]);
    ASYNC_COPY16(srcB,      &xs[0][2 * wave + 1][0]);
    ASYNC_COPY16(srcA + 64, &xs[1][2 * wave][0]);
    ASYNC_COPY16(srcB + 64, &xs[1][2 * wave + 1][0]);
    srcA += 128; srcB += 128;            // now point at chunk 2
    // phi chunk 0 -> pA
    pA[0] = *pb0; pA[1] = *pb1; pA[2] = *pb2;
    pA[3] = *pb3; pA[4] = *pb4; pA[5] = *pb5;
    pb0 += 64; pb1 += 64; pb2 += 64; pb3 += 64; pb4 += 64; pb5 += 64;
    __builtin_amdgcn_sched_barrier(0);

    int bc = 0;   // buffer holding chunk c
    int bf = 2;   // buffer to fill with chunk c+2

    // one pipeline body; PC = phi regs for chunk c, PN = regs to prefill
#define PROJ_BODY(PC, PN, C_)                                                  \
    {                                                                          \
        if ((C_) == 0 || (C_) == 31)                                           \
            asm volatile("s_waitcnt vmcnt(0)" ::: "memory");                   \
        else                                                                   \
            asm volatile("s_waitcnt vmcnt(2)" ::: "memory");                   \
        __builtin_amdgcn_sched_barrier(0);                                     \
        __builtin_amdgcn_s_barrier();                                          \
        __builtin_amdgcn_sched_barrier(0);                                     \
        if ((C_) < 31) {                                                       \
            PN[0] = *pb0; PN[1] = *pb1; PN[2] = *pb2;                          \
            PN[3] = *pb3; PN[4] = *pb4; PN[5] = *pb5;                          \
            pb0 += 64; pb1 += 64; pb2 += 64;                                   \
            pb3 += 64; pb4 += 64; pb5 += 64;                                   \
        }                                                                      \
        __builtin_amdgcn_sched_barrier(0);                                     \
        if ((C_) < 30) {                                                       \
            ASYNC_COPY16(srcA, &xs[bf][2 * wave][0]);                          \
            ASYNC_COPY16(srcB, &xs[bf][2 * wave + 1][0]);                      \
            srcA += 64; srcB += 64;                                            \
        }                                                                      \
        __builtin_amdgcn_sched_barrier(0);                                     \
        _Pragma("unroll")                                                      \
        for (int r = 0; r < 8; ++r) {                                          \
            const float4 xv = xs[bc][r][lane];                                 \
            DOT4(acc[r][0], PC[0], xv);                                        \
            DOT4(acc[r][1], PC[1], xv);                                        \
            DOT4(acc[r][2], PC[2], xv);                                        \
            DOT4(acc[r][3], PC[3], xv);                                        \
            DOT4(acc[r][4], PC[4], xv);                                        \
            DOT4(acc[r][5], PC[5], xv);                                        \
            if (r == wr0)      DOT4(ssq0, xv, xv)                              \
            else if (r == wr1) DOT4(ssq1, xv, xv)                              \
        }                                                                      \
        bc = (bc == 2) ? 0 : bc + 1;                                           \
        bf = (bf == 2) ? 0 : bf + 1;                                           \
    }

#pragma unroll 1
    for (int c = 0; c < 32; c += 2) {
        PROJ_BODY(pA, pB, c);
        PROJ_BODY(pB, pA, c + 1);
    }
#undef PROJ_BODY

    // butterfly reduce across all 64 lanes (lanes cover distinct K positions)
#pragma unroll
    for (int r = 0; r < 8; ++r)
#pragma unroll
        for (int j = 0; j < 6; ++j) {
            float v = acc[r][j];
#pragma unroll
            for (int off = 32; off > 0; off >>= 1)
                v += __shfl_xor(v, off, 64);
            acc[r][j] = v;
        }
#pragma unroll
    for (int off = 32; off > 0; off >>= 1)
        ssq0 += __shfl_xor(ssq0, off, 64);
#pragma unroll
    for (int off = 32; off > 0; off >>= 1)
        ssq1 += __shfl_xor(ssq1, off, 64);

    if (lane == 0) {
#pragma unroll
        for (int r = 0; r < 8; ++r)
#pragma unroll
            for (int j = 0; j < 6; ++j)
                red[wave][r][j] = acc[r][j];
        redss[2 * wave]     = ssq0;
        redss[2 * wave + 1] = ssq1;
    }
    __syncthreads();

    // final gather; 200 threads -> dots_part[kb][8 rows][25]
    const int t = threadIdx.x;
    if (t < 200) {
        const int r = t / 25, o = t % 25;
        float s;
        if (o < 24) s = red[o / 6][r][o % 6];   // phi row o handled by wave o/6
        else        s = redss[r];               // ssq of row r
        dots_part[((size_t)kb * B_ROWS + (b0 + r)) * 25 + o] = s;
    }
}

// ---------------------------------------------------------------------------
// Kernel 2: per-row finalize: sum K-halves, rms factor, softmax, 2*sigmoid,
// Sinkhorn(20).
// dots layout: [0..3]=pre, [4..7]=post, [8..23]=res, [24]=ssq
// params layout: [0..3]=H_pre, [4..7]=H_post, [8..23]=M (row-major 4x4)
// ---------------------------------------------------------------------------
__global__ void finalize_kernel(
    const float* __restrict__ dots_part,
    const float* __restrict__ b_pre,
    const float* __restrict__ b_post,
    const float* __restrict__ b_res,
    const float* __restrict__ alpha_pre,
    const float* __restrict__ alpha_post,
    const float* __restrict__ alpha_res,
    float* __restrict__ params)
{
    const int row = blockIdx.x * blockDim.x + threadIdx.x;
    if (row >= B_ROWS) return;

    const float* d0 = dots_part + (size_t)row * 25;
    const float* d1 = dots_part + ((size_t)B_ROWS + row) * 25;
    float d[25];
#pragma unroll
    for (int o = 0; o < 25; ++o) d[o] = d0[o] + d1[o];

    const float inv_rms = rsqrtf(d[24] * (1.f / (float)NC) + 1e-8f);
    const float ap  = alpha_pre[0];
    const float apo = alpha_post[0];
    const float ar  = alpha_res[0];

    // softmax(h_pre)
    float hp[4];
    float mx = -1e30f;
#pragma unroll
    for (int j = 0; j < 4; ++j) {
        hp[j] = ap * d[j] * inv_rms + b_pre[j];
        mx = fmaxf(mx, hp[j]);
    }
    float e[4], s = 0.f;
#pragma unroll
    for (int j = 0; j < 4; ++j) { e[j] = expf(hp[j] - mx); s += e[j]; }
    float Hpre[4];
#pragma unroll
    for (int j = 0; j < 4; ++j) Hpre[j] = e[j] / s;

    // 2*sigmoid(h_post)
    float Hpost[4];
#pragma unroll
    for (int j = 0; j < 4; ++j) {
        const float h = apo * d[4 + j] * inv_rms + b_post[j];
        Hpost[j] = 2.f / (1.f + expf(-h));
    }

    // Sinkhorn on exp(h_res)
    float M[16];
#pragma unroll
    for (int k = 0; k < 16; ++k)
        M[k] = expf(ar * d[8 + k] * inv_rms + b_res[k]);

    for (int it = 0; it < 20; ++it) {
#pragma unroll
        for (int i = 0; i < 4; ++i) {
            const float rs = M[i*4+0] + M[i*4+1] + M[i*4+2] + M[i*4+3] + 1e-8f;
#pragma unroll
            for (int j = 0; j < 4; ++j) M[i*4+j] = M[i*4+j] / rs;
        }
#pragma unroll
        for (int j = 0; j < 4; ++j) {
            const float cs = M[0*4+j] + M[1*4+j] + M[2*4+j] + M[3*4+j] + 1e-8f;
#pragma unroll
            for (int i = 0; i < 4; ++i) M[i*4+j] = M[i*4+j] / cs;
        }
    }

    float* p = params + (size_t)row * 24;
#pragma unroll
    for (int j = 0; j < 4; ++j)  p[j]     = Hpre[j];
#pragma unroll
    for (int j = 0; j < 4; ++j)  p[4 + j] = Hpost[j];
#pragma unroll
    for (int k = 0; k < 16; ++k) p[8 + k] = M[k];
}

// ---------------------------------------------------------------------------
// Kernel 3: output. One block per batch row; x row held in registers
// (64 floats/thread), block-reduced RMS of x_agg, then fused epilogue.
// ---------------------------------------------------------------------------
__global__ __launch_bounds__(256, 2) void out_kernel(
    const float* __restrict__ x,
    const float* __restrict__ w,
    const float* __restrict__ params,
    float* __restrict__ out)
{
    const float4* __restrict__ x4 = reinterpret_cast<const float4*>(x);
    const float4* __restrict__ w4 = reinterpret_cast<const float4*>(w);
    float4* __restrict__ out4 = reinterpret_cast<float4*>(out);

    const int b = blockIdx.x;
    const float* __restrict__ p = params + (size_t)b * 24;

    float Hpre[4], Hpost[4], M[16];
#pragma unroll
    for (int j = 0; j < 4; ++j)  Hpre[j]  = p[j];
#pragma unroll
    for (int j = 0; j < 4; ++j)  Hpost[j] = p[4 + j];
#pragma unroll
    for (int k = 0; k < 16; ++k) M[k]     = p[8 + k];

    const int t = threadIdx.x;
    const size_t base = (size_t)b * NC4;

    float4 xv[4][4];
    float4 agg[4];
    float ssq = 0.f;

#pragma unroll
    for (int u = 0; u < 4; ++u) {
        const int c4 = u * 256 + t;
#pragma unroll
        for (int n = 0; n < 4; ++n)
            xv[u][n] = x4[base + (size_t)n * C4 + c4];

        float4 a;
        a.x = Hpre[0]*xv[u][0].x + Hpre[1]*xv[u][1].x + Hpre[2]*xv[u][2].x + Hpre[3]*xv[u][3].x;
        a.y = Hpre[0]*xv[u][0].y + Hpre[1]*xv[u][1].y + Hpre[2]*xv[u][2].y + Hpre[3]*xv[u][3].y;
        a.z = Hpre[0]*xv[u][0].z + Hpre[1]*xv[u][1].z + Hpre[2]*xv[u][2].z + Hpre[3]*xv[u][3].z;
        a.w = Hpre[0]*xv[u][0].w + Hpre[1]*xv[u][1].w + Hpre[2]*xv[u][2].w + Hpre[3]*xv[u][3].w;
        agg[u] = a;
        ssq += a.x*a.x + a.y*a.y + a.z*a.z + a.w*a.w;
    }

#pragma unroll
    for (int off = 32; off > 0; off >>= 1)
        ssq += __shfl_xor(ssq, off, 64);
    __shared__ float red[4];
    if ((t & 63) == 0) red[t >> 6] = ssq;
    __syncthreads();
    const float total = red[0] + red[1] + red[2] + red[3];
    const float inv = rsqrtf(total * (1.f / (float)C_DIM) + 1e-5f);

#pragma unroll
    for (int u = 0; u < 4; ++u) {
        const int c4 = u * 256 + t;
        const float4 wv = w4[c4];
        float4 y;
        y.x = agg[u].x * inv * wv.x;
        y.y = agg[u].y * inv * wv.y;
        y.z = agg[u].z * inv * wv.z;
        y.w = agg[u].w * inv * wv.w;

#pragma unroll
        for (int i = 0; i < 4; ++i) {
            float4 o;
            o.x = Hpost[i]*y.x + M[i*4+0]*xv[u][0].x + M[i*4+1]*xv[u][1].x
                               + M[i*4+2]*xv[u][2].x + M[i*4+3]*xv[u][3].x;
            o.y = Hpost[i]*y.y + M[i*4+0]*xv[u][0].y + M[i*4+1]*xv[u][1].y
                               + M[i*4+2]*xv[u][2].y + M[i*4+3]*xv[u][3].y;
            o.z = Hpost[i]*y.z + M[i*4+0]*xv[u][0].z + M[i*4+1]*xv[u][1].z
                               + M[i*4+2]*xv[u][2].z + M[i*4+3]*xv[u][3].z;
            o.w = Hpost[i]*y.w + M[i*4+0]*xv[u][0].w + M[i*4+1]*xv[u][1].w
                               + M[i*4+2]*xv[u][2].w + M[i*4+3]*xv[u][3].w;
            out4[base + (size_t)i * C4 + c4] = o;
        }
    }
}

// ---------------------------------------------------------------------------
extern "C" void kernel_launch(void* const* d_in, const int* in_sizes, int n_in,
                              void* d_out, int out_size, void* d_ws, size_t ws_size,
                              hipStream_t stream) {
    const float* x        = (const float*)d_in[0];
    const float* w        = (const float*)d_in[1];
    const float* phi_pre  = (const float*)d_in[2];
    const float* phi_post = (const float*)d_in[3];
    const float* phi_res  = (const float*)d_in[4];
    const float* b_pre    = (const float*)d_in[5];
    const float* b_post   = (const float*)d_in[6];
    const float* b_res    = (const float*)d_in[7];
    const float* a_pre    = (const float*)d_in[8];
    const float* a_post   = (const float*)d_in[9];
    const float* a_res    = (const float*)d_in[10];
    float* out = (float*)d_out;

    float* dots_part = (float*)d_ws;                        // [2][4096][25]
    float* params    = dots_part + (size_t)2 * B_ROWS * 25; // [4096][24]

    hipLaunchKernelGGL(proj_kernel, dim3(B_ROWS / 4), dim3(256), 0, stream,
                       x, phi_pre, phi_post, phi_res, dots_part);
    hipLaunchKernelGGL(finalize_kernel, dim3(B_ROWS / 256), dim3(256), 0, stream,
                       dots_part, b_pre, b_post, b_res, a_pre, a_post, a_res, params);
    hipLaunchKernelGGL(out_kernel, dim3(B_ROWS), dim3(256), 0, stream,
                       x, w, params, out);
}

// Round 14
// 209.744 us; speedup vs baseline: 2.7404x; 2.7404x over previous
//
#include <hip/hip_runtime.h>
#include <math.h>

#define B_ROWS 4096
#define NSTR 4
#define C_DIM 4096
#define NC 16384      // NSTR*C_DIM
#define NC4 4096      // NC/4 (float4 per batch row)
#define C4 1024       // C_DIM/4 (float4 per stream)

// async global->LDS DMA, 16B per lane. LDS dest must be wave-uniform base;
// lane l writes base + l*16. Global src is per-lane.
// aux=2 == CPol::NT (non-temporal): x has zero L2 reuse in this kernel, so
// stream it past L2 to keep the 24 phi rows (1.5MB) L2-resident.
#define ASYNC_COPY16_NT(g, l)                                                  \
    __builtin_amdgcn_global_load_lds(                                         \
        (const __attribute__((address_space(1))) void*)(g),                   \
        (__attribute__((address_space(3))) void*)(l), 16, 0, 2)

#define DOT4(A, P, XV) { float _a = (A);                                       \
    _a = fmaf((XV).x, (P).x, _a); _a = fmaf((XV).y, (P).y, _a);                \
    _a = fmaf((XV).z, (P).z, _a); _a = fmaf((XV).w, (P).w, _a); (A) = _a; }

// ---------------------------------------------------------------------------
// Kernel 1: projections. Grid = (B_ROWS/8) x 2 K-halves -> 1024 blocks of
// 256 threads (4 waves). Block = 8 batch rows x one K-half (2048 float4).
// Wave w owns phi rows 6w..6w+5 (direct pre/post/res pointer select) and
// DMA-stages x rows 2w,2w+1. R12 schedule (best known: 203us total).
//
// R13 POST-MORTEM: phi register-prefetch (pA/pB, +48 VGPR) blew the 128-VGPR
// cap -> 1GB scratch spill, VALUBusy 8.8%. Reverted. R14 theory: proj's
// residual (~114us vs ~55 floor) is phi being EVICTED from L2 by the x
// stream -> phi served from L3 (~67us fabric) serializing with x HBM
// (~41us). Fix: NT cache policy on the x DMAs (x has no L2 reuse here).
//
// Schedule per iter c (counted vmcnt, 3 buffers, chunk=64 float4/row):
//   [s_waitcnt vmcnt(8): chunk c's DMAs retired (in-order); phi(c-1)x6 +
//    dma(c+1)x2 still outstanding]
//   [raw s_barrier - no vmcnt(0) drain]
//   [6 phi loads for chunk c FIRST (before new DMA: in-order vmcnt means
//    phi waits would otherwise chain on the DMA)]
//   [DMA chunk c+2 -> buf bf (holds c-1, consumed by all: WAR-safe)]
//   [consume: 8 ds_read_b128 + 200 FMA]
// LDS 24KB -> 4 blocks/CU resident; ~95 live floats < 128 VGPR cap.
// ---------------------------------------------------------------------------
__global__ __launch_bounds__(256, 4) void proj_kernel(
    const float* __restrict__ x,
    const float* __restrict__ phi_pre,
    const float* __restrict__ phi_post,
    const float* __restrict__ phi_res,
    float* __restrict__ dots_part)   // [2][B_ROWS][25]
{
    const float4* __restrict__ x4    = reinterpret_cast<const float4*>(x);
    const float4* __restrict__ pre4  = reinterpret_cast<const float4*>(phi_pre);
    const float4* __restrict__ post4 = reinterpret_cast<const float4*>(phi_post);
    const float4* __restrict__ res4  = reinterpret_cast<const float4*>(phi_res);

    const int bid  = blockIdx.x;
    const int kb   = bid & 1;            // K-half
    const int b0   = (bid >> 1) * 8;     // first batch row
    const int wave = threadIdx.x >> 6;   // 0..3
    const int lane = threadIdx.x & 63;
    const int wv   = __builtin_amdgcn_readfirstlane(wave);
    const int wr0  = 2 * wv;             // this wave's own rows (ssq)
    const int wr1  = 2 * wv + 1;

    __shared__ float4 xs[3][8][64];      // [buf][row][float4] = 24 KB
    __shared__ float  red[4][8][6];      // [wave][row][j]
    __shared__ float  redss[8];          // ssq per row

    const int kbase = kb * 2048;         // float4 index where this K-half starts

    // x staging pointers (advance by 64/iter; point at current chunk c)
    const float4* srcA = x4 + (size_t)(b0 + 2 * wave)     * NC4 + kbase + lane;
    const float4* srcB = x4 + (size_t)(b0 + 2 * wave + 1) * NC4 + kbase + lane;

    // wave's 6 phi row pointers, direct from the three inputs (no repack).
    const int row0 = wv * 6;
    auto rowbase = [&](int row) -> const float4* {
        if (row < 4)  return pre4  + (size_t)row * NC4;
        if (row < 8)  return post4 + (size_t)(row - 4) * NC4;
        return res4 + (size_t)(row - 8) * NC4;
    };
    const float4* pb0 = rowbase(row0 + 0) + kbase + lane;
    const float4* pb1 = rowbase(row0 + 1) + kbase + lane;
    const float4* pb2 = rowbase(row0 + 2) + kbase + lane;
    const float4* pb3 = rowbase(row0 + 3) + kbase + lane;
    const float4* pb4 = rowbase(row0 + 4) + kbase + lane;
    const float4* pb5 = rowbase(row0 + 5) + kbase + lane;

    float acc[8][6];
#pragma unroll
    for (int r = 0; r < 8; ++r)
#pragma unroll
        for (int j = 0; j < 6; ++j) acc[r][j] = 0.f;
    float ssq0 = 0.f, ssq1 = 0.f;

    // ---- prologue: DMA chunk 0 -> buf0, chunk 1 -> buf1 (4 vmem ops) ----
    ASYNC_COPY16_NT(srcA,      &xs[0][2 * wave][0]);
    ASYNC_COPY16_NT(srcB,      &xs[0][2 * wave + 1][0]);
    ASYNC_COPY16_NT(srcA + 64, &xs[1][2 * wave][0]);
    ASYNC_COPY16_NT(srcB + 64, &xs[1][2 * wave + 1][0]);
    __builtin_amdgcn_sched_barrier(0);

    int bc = 0;   // buffer holding chunk c
    int bf = 2;   // buffer to fill with chunk c+2

#pragma unroll 1
    for (int c = 0; c < 32; ++c) {
        // -- 1. counted wait: chunk c's 2 DMAs retired (in-order counter).
        if (c == 0)       asm volatile("s_waitcnt vmcnt(2)" ::: "memory");
        else if (c == 31) asm volatile("s_waitcnt vmcnt(0)" ::: "memory");
        else              asm volatile("s_waitcnt vmcnt(8)" ::: "memory");
        __builtin_amdgcn_sched_barrier(0);
        __builtin_amdgcn_s_barrier();        // raw: no vmcnt(0) drain
        __builtin_amdgcn_sched_barrier(0);

        // -- 2. phi loads for chunk c FIRST (before any new DMA) --
        const float4 p0 = *pb0;
        const float4 p1 = *pb1;
        const float4 p2 = *pb2;
        const float4 p3 = *pb3;
        const float4 p4 = *pb4;
        const float4 p5 = *pb5;
        __builtin_amdgcn_sched_barrier(0);

        // -- 3. prefetch chunk c+2 into bf --
        if (c < 30) {
            ASYNC_COPY16_NT(srcA + 128, &xs[bf][2 * wave][0]);
            ASYNC_COPY16_NT(srcB + 128, &xs[bf][2 * wave + 1][0]);
        }
        __builtin_amdgcn_sched_barrier(0);

        // -- 4. consume chunk c: 8 ds_read_b128 + 200 FMAs --
#pragma unroll
        for (int r = 0; r < 8; ++r) {
            const float4 xv = xs[bc][r][lane];
            DOT4(acc[r][0], p0, xv);
            DOT4(acc[r][1], p1, xv);
            DOT4(acc[r][2], p2, xv);
            DOT4(acc[r][3], p3, xv);
            DOT4(acc[r][4], p4, xv);
            DOT4(acc[r][5], p5, xv);
            if (r == wr0)      DOT4(ssq0, xv, xv)
            else if (r == wr1) DOT4(ssq1, xv, xv)
        }

        // advance
        srcA += 64; srcB += 64;
        pb0 += 64; pb1 += 64; pb2 += 64; pb3 += 64; pb4 += 64; pb5 += 64;
        bc = (bc == 2) ? 0 : bc + 1;
        bf = (bf == 2) ? 0 : bf + 1;
    }

    // butterfly reduce across all 64 lanes (lanes cover distinct K positions)
#pragma unroll
    for (int r = 0; r < 8; ++r)
#pragma unroll
        for (int j = 0; j < 6; ++j) {
            float v = acc[r][j];
#pragma unroll
            for (int off = 32; off > 0; off >>= 1)
                v += __shfl_xor(v, off, 64);
            acc[r][j] = v;
        }
#pragma unroll
    for (int off = 32; off > 0; off >>= 1)
        ssq0 += __shfl_xor(ssq0, off, 64);
#pragma unroll
    for (int off = 32; off > 0; off >>= 1)
        ssq1 += __shfl_xor(ssq1, off, 64);

    if (lane == 0) {
#pragma unroll
        for (int r = 0; r < 8; ++r)
#pragma unroll
            for (int j = 0; j < 6; ++j)
                red[wave][r][j] = acc[r][j];
        redss[2 * wave]     = ssq0;
        redss[2 * wave + 1] = ssq1;
    }
    __syncthreads();

    // final gather; 200 threads -> dots_part[kb][8 rows][25]
    const int t = threadIdx.x;
    if (t < 200) {
        const int r = t / 25, o = t % 25;
        float s;
        if (o < 24) s = red[o / 6][r][o % 6];   // phi row o handled by wave o/6
        else        s = redss[r];               // ssq of row r
        dots_part[((size_t)kb * B_ROWS + (b0 + r)) * 25 + o] = s;
    }
}

// ---------------------------------------------------------------------------
// Kernel 2: per-row finalize: sum K-halves, rms factor, softmax, 2*sigmoid,
// Sinkhorn(20).
// dots layout: [0..3]=pre, [4..7]=post, [8..23]=res, [24]=ssq
// params layout: [0..3]=H_pre, [4..7]=H_post, [8..23]=M (row-major 4x4)
// ---------------------------------------------------------------------------
__global__ void finalize_kernel(
    const float* __restrict__ dots_part,
    const float* __restrict__ b_pre,
    const float* __restrict__ b_post,
    const float* __restrict__ b_res,
    const float* __restrict__ alpha_pre,
    const float* __restrict__ alpha_post,
    const float* __restrict__ alpha_res,
    float* __restrict__ params)
{
    const int row = blockIdx.x * blockDim.x + threadIdx.x;
    if (row >= B_ROWS) return;

    const float* d0 = dots_part + (size_t)row * 25;
    const float* d1 = dots_part + ((size_t)B_ROWS + row) * 25;
    float d[25];
#pragma unroll
    for (int o = 0; o < 25; ++o) d[o] = d0[o] + d1[o];

    const float inv_rms = rsqrtf(d[24] * (1.f / (float)NC) + 1e-8f);
    const float ap  = alpha_pre[0];
    const float apo = alpha_post[0];
    const float ar  = alpha_res[0];

    // softmax(h_pre)
    float hp[4];
    float mx = -1e30f;
#pragma unroll
    for (int j = 0; j < 4; ++j) {
        hp[j] = ap * d[j] * inv_rms + b_pre[j];
        mx = fmaxf(mx, hp[j]);
    }
    float e[4], s = 0.f;
#pragma unroll
    for (int j = 0; j < 4; ++j) { e[j] = expf(hp[j] - mx); s += e[j]; }
    float Hpre[4];
#pragma unroll
    for (int j = 0; j < 4; ++j) Hpre[j] = e[j] / s;

    // 2*sigmoid(h_post)
    float Hpost[4];
#pragma unroll
    for (int j = 0; j < 4; ++j) {
        const float h = apo * d[4 + j] * inv_rms + b_post[j];
        Hpost[j] = 2.f / (1.f + expf(-h));
    }

    // Sinkhorn on exp(h_res)
    float M[16];
#pragma unroll
    for (int k = 0; k < 16; ++k)
        M[k] = expf(ar * d[8 + k] * inv_rms + b_res[k]);

    for (int it = 0; it < 20; ++it) {
#pragma unroll
        for (int i = 0; i < 4; ++i) {
            const float rs = M[i*4+0] + M[i*4+1] + M[i*4+2] + M[i*4+3] + 1e-8f;
#pragma unroll
            for (int j = 0; j < 4; ++j) M[i*4+j] = M[i*4+j] / rs;
        }
#pragma unroll
        for (int j = 0; j < 4; ++j) {
            const float cs = M[0*4+j] + M[1*4+j] + M[2*4+j] + M[3*4+j] + 1e-8f;
#pragma unroll
            for (int i = 0; i < 4; ++i) M[i*4+j] = M[i*4+j] / cs;
        }
    }

    float* p = params + (size_t)row * 24;
#pragma unroll
    for (int j = 0; j < 4; ++j)  p[j]     = Hpre[j];
#pragma unroll
    for (int j = 0; j < 4; ++j)  p[4 + j] = Hpost[j];
#pragma unroll
    for (int k = 0; k < 16; ++k) p[8 + k] = M[k];
}

// ---------------------------------------------------------------------------
// Kernel 3: output. One block per batch row; x row held in registers
// (64 floats/thread), block-reduced RMS of x_agg, then fused epilogue.
// ---------------------------------------------------------------------------
__global__ __launch_bounds__(256, 2) void out_kernel(
    const float* __restrict__ x,
    const float* __restrict__ w,
    const float* __restrict__ params,
    float* __restrict__ out)
{
    const float4* __restrict__ x4 = reinterpret_cast<const float4*>(x);
    const float4* __restrict__ w4 = reinterpret_cast<const float4*>(w);
    float4* __restrict__ out4 = reinterpret_cast<float4*>(out);

    const int b = blockIdx.x;
    const float* __restrict__ p = params + (size_t)b * 24;

    float Hpre[4], Hpost[4], M[16];
#pragma unroll
    for (int j = 0; j < 4; ++j)  Hpre[j]  = p[j];
#pragma unroll
    for (int j = 0; j < 4; ++j)  Hpost[j] = p[4 + j];
#pragma unroll
    for (int k = 0; k < 16; ++k) M[k]     = p[8 + k];

    const int t = threadIdx.x;
    const size_t base = (size_t)b * NC4;

    float4 xv[4][4];
    float4 agg[4];
    float ssq = 0.f;

#pragma unroll
    for (int u = 0; u < 4; ++u) {
        const int c4 = u * 256 + t;
#pragma unroll
        for (int n = 0; n < 4; ++n)
            xv[u][n] = x4[base + (size_t)n * C4 + c4];

        float4 a;
        a.x = Hpre[0]*xv[u][0].x + Hpre[1]*xv[u][1].x + Hpre[2]*xv[u][2].x + Hpre[3]*xv[u][3].x;
        a.y = Hpre[0]*xv[u][0].y + Hpre[1]*xv[u][1].y + Hpre[2]*xv[u][2].y + Hpre[3]*xv[u][3].y;
        a.z = Hpre[0]*xv[u][0].z + Hpre[1]*xv[u][1].z + Hpre[2]*xv[u][2].z + Hpre[3]*xv[u][3].z;
        a.w = Hpre[0]*xv[u][0].w + Hpre[1]*xv[u][1].w + Hpre[2]*xv[u][2].w + Hpre[3]*xv[u][3].w;
        agg[u] = a;
        ssq += a.x*a.x + a.y*a.y + a.z*a.z + a.w*a.w;
    }

#pragma unroll
    for (int off = 32; off > 0; off >>= 1)
        ssq += __shfl_xor(ssq, off, 64);
    __shared__ float red[4];
    if ((t & 63) == 0) red[t >> 6] = ssq;
    __syncthreads();
    const float total = red[0] + red[1] + red[2] + red[3];
    const float inv = rsqrtf(total * (1.f / (float)C_DIM) + 1e-5f);

#pragma unroll
    for (int u = 0; u < 4; ++u) {
        const int c4 = u * 256 + t;
        const float4 wv = w4[c4];
        float4 y;
        y.x = agg[u].x * inv * wv.x;
        y.y = agg[u].y * inv * wv.y;
        y.z = agg[u].z * inv * wv.z;
        y.w = agg[u].w * inv * wv.w;

#pragma unroll
        for (int i = 0; i < 4; ++i) {
            float4 o;
            o.x = Hpost[i]*y.x + M[i*4+0]*xv[u][0].x + M[i*4+1]*xv[u][1].x
                               + M[i*4+2]*xv[u][2].x + M[i*4+3]*xv[u][3].x;
            o.y = Hpost[i]*y.y + M[i*4+0]*xv[u][0].y + M[i*4+1]*xv[u][1].y
                               + M[i*4+2]*xv[u][2].y + M[i*4+3]*xv[u][3].y;
            o.z = Hpost[i]*y.z + M[i*4+0]*xv[u][0].z + M[i*4+1]*xv[u][1].z
                               + M[i*4+2]*xv[u][2].z + M[i*4+3]*xv[u][3].z;
            o.w = Hpost[i]*y.w + M[i*4+0]*xv[u][0].w + M[i*4+1]*xv[u][1].w
                               + M[i*4+2]*xv[u][2].w + M[i*4+3]*xv[u][3].w;
            out4[base + (size_t)i * C4 + c4] = o;
        }
    }
}

// ---------------------------------------------------------------------------
extern "C" void kernel_launch(void* const* d_in, const int* in_sizes, int n_in,
                              void* d_out, int out_size, void* d_ws, size_t ws_size,
                              hipStream_t stream) {
    const float* x        = (const float*)d_in[0];
    const float* w        = (const float*)d_in[1];
    const float* phi_pre  = (const float*)d_in[2];
    const float* phi_post = (const float*)d_in[3];
    const float* phi_res  = (const float*)d_in[4];
    const float* b_pre    = (const float*)d_in[5];
    const float* b_post   = (const float*)d_in[6];
    const float* b_res    = (const float*)d_in[7];
    const float* a_pre    = (const float*)d_in[8];
    const float* a_post   = (const float*)d_in[9];
    const float* a_res    = (const float*)d_in[10];
    float* out = (float*)d_out;

    float* dots_part = (float*)d_ws;                        // [2][4096][25]
    float* params    = dots_part + (size_t)2 * B_ROWS * 25; // [4096][24]

    hipLaunchKernelGGL(proj_kernel, dim3(B_ROWS / 4), dim3(256), 0, stream,
                       x, phi_pre, phi_post, phi_res, dots_part);
    hipLaunchKernelGGL(finalize_kernel, dim3(B_ROWS / 256), dim3(256), 0, stream,
                       dots_part, b_pre, b_post, b_res, a_pre, a_post, a_res, params);
    hipLaunchKernelGGL(out_kernel, dim3(B_ROWS), dim3(256), 0, stream,
                       x, w, params, out);
}

// Round 16
// 192.852 us; speedup vs baseline: 2.9804x; 1.0876x over previous
//
#include <hip/hip_runtime.h>
#include <math.h>

#define B_ROWS 4096
#define NSTR 4
#define C_DIM 4096
#define NC 16384      // NSTR*C_DIM
#define NC4 4096      // NC/4 (float4 per batch row)
#define C4 1024       // C_DIM/4 (float4 per stream)

// clang's amdgcn builtins (cvt_pkrtz "V2hff", fdot2 "fV2hV2hfb") use __fp16
// vectors -- NOT _Float16 vectors (R15 compile failure). Use __fp16 throughout.
typedef __fp16 half2_t __attribute__((ext_vector_type(2)));
typedef __fp16 half4_t __attribute__((ext_vector_type(4)));

// async global->LDS DMA, 16B per lane. LDS dest must be wave-uniform base;
// lane l writes base + l*16. Global src is per-lane. (aux=0: R14 showed NT
// was a slight regression -> reverted.)
#define ASYNC_COPY16(g, l)                                                     \
    __builtin_amdgcn_global_load_lds(                                         \
        (const __attribute__((address_space(1))) void*)(g),                   \
        (__attribute__((address_space(3))) void*)(l), 16, 0, 0)

#define DOT4(A, P, XV) { float _a = (A);                                       \
    _a = fmaf((XV).x, (P).x, _a); _a = fmaf((XV).y, (P).y, _a);                \
    _a = fmaf((XV).z, (P).z, _a); _a = fmaf((XV).w, (P).w, _a); (A) = _a; }

// ---------------------------------------------------------------------------
// Kernel 0: repack phi into one contiguous f16 buffer [24][16384] halves.
// Row order: [pre0..3, post0..3, res0..15]. Halves phi fabric traffic and
// enables v_dot2_f32_f16 in the proj inner loop. f32->f16 via cvt_pkrtz
// (no scalar __fp16 ops).
// ---------------------------------------------------------------------------
__global__ void repack16_kernel(
    const float4* __restrict__ pre4,
    const float4* __restrict__ post4,
    const float4* __restrict__ res4,
    half4_t* __restrict__ ws16)
{
    const int idx = blockIdx.x * blockDim.x + threadIdx.x;   // 0 .. 24*4096-1
    if (idx >= 24 * NC4) return;
    const int row = idx / NC4;
    const int k4  = idx % NC4;
    float4 v;
    if (row < 4)        v = pre4[row * NC4 + k4];
    else if (row < 8)   v = post4[(row - 4) * NC4 + k4];
    else                v = res4[(row - 8) * NC4 + k4];
    const half2_t lo = __builtin_amdgcn_cvt_pkrtz(v.x, v.y);
    const half2_t hi = __builtin_amdgcn_cvt_pkrtz(v.z, v.w);
    ws16[idx] = __builtin_shufflevector(lo, hi, 0, 1, 2, 3);
}

// ---------------------------------------------------------------------------
// Kernel 1: projections. Grid = (B_ROWS/8) x 2 K-halves -> 1024 blocks of
// 256 threads (4 waves). Block = 8 batch rows x one K-half (2048 float4).
// Wave w owns phi rows 6w..6w+5 (f16-packed ws) and DMA-stages x rows 2w,2w+1.
//
// R12 schedule (best known, 203us) + f16-dot change: inner dot math via
// v_dot2_f32_f16 (2 MACs/instr) on f16 phi + cvt_pkrtz'd x. R10 PMC showed
// VALUBusy 62% -> issue-bound; this cuts per-iter issue ~223 -> ~145 instrs
// and halves phi fabric bytes (805 -> 402 MB). ssq stays f32 (rsqrt input).
//
// Schedule per iter c (counted vmcnt, 3 buffers, chunk=64 float4/row):
//   [s_waitcnt vmcnt(8): chunk c's DMAs retired (in-order); phi(c-1)x6 +
//    dma(c+1)x2 still outstanding]
//   [raw s_barrier - no vmcnt(0) drain]
//   [6 phi f16 loads for chunk c FIRST (before new DMA: in-order vmcnt)]
//   [DMA chunk c+2 -> buf bf (holds c-1, consumed by all: WAR-safe)]
//   [consume: 8 ds_read_b128 + 16 cvt_pkrtz + 96 fdot2 + 8 ssq-FMA]
// LDS 24KB -> 4 blocks/CU resident; ~90 live floats < 128 VGPR cap.
// ---------------------------------------------------------------------------
__global__ __launch_bounds__(256, 4) void proj_kernel(
    const float* __restrict__ x,
    const half4_t* __restrict__ phi16,   // [24][4096] half4
    float* __restrict__ dots_part)       // [2][B_ROWS][25]
{
    const float4* __restrict__ x4 = reinterpret_cast<const float4*>(x);

    const int bid  = blockIdx.x;
    const int kb   = bid & 1;            // K-half
    const int b0   = (bid >> 1) * 8;     // first batch row
    const int wave = threadIdx.x >> 6;   // 0..3
    const int lane = threadIdx.x & 63;
    const int wv   = __builtin_amdgcn_readfirstlane(wave);
    const int wr0  = 2 * wv;             // this wave's own rows (ssq)
    const int wr1  = 2 * wv + 1;

    __shared__ float4 xs[3][8][64];      // [buf][row][float4] = 24 KB
    __shared__ float  red[4][8][6];      // [wave][row][j]
    __shared__ float  redss[8];          // ssq per row

    const int kbase = kb * 2048;         // float4 index where this K-half starts

    // x staging pointers (advance by 64/iter; point at current chunk c)
    const float4* srcA = x4 + (size_t)(b0 + 2 * wave)     * NC4 + kbase + lane;
    const float4* srcB = x4 + (size_t)(b0 + 2 * wave + 1) * NC4 + kbase + lane;

    // wave's 6 phi row pointers into the f16 ws (wave-uniform bases)
    const int row0 = wv * 6;
    const half4_t* pb0 = phi16 + (size_t)(row0 + 0) * NC4 + kbase + lane;
    const half4_t* pb1 = phi16 + (size_t)(row0 + 1) * NC4 + kbase + lane;
    const half4_t* pb2 = phi16 + (size_t)(row0 + 2) * NC4 + kbase + lane;
    const half4_t* pb3 = phi16 + (size_t)(row0 + 3) * NC4 + kbase + lane;
    const half4_t* pb4 = phi16 + (size_t)(row0 + 4) * NC4 + kbase + lane;
    const half4_t* pb5 = phi16 + (size_t)(row0 + 5) * NC4 + kbase + lane;

    float acc[8][6];
#pragma unroll
    for (int r = 0; r < 8; ++r)
#pragma unroll
        for (int j = 0; j < 6; ++j) acc[r][j] = 0.f;
    float ssq0 = 0.f, ssq1 = 0.f;

    // ---- prologue: DMA chunk 0 -> buf0, chunk 1 -> buf1 (4 vmem ops) ----
    ASYNC_COPY16(srcA,      &xs[0][2 * wave][0]);
    ASYNC_COPY16(srcB,      &xs[0][2 * wave + 1][0]);
    ASYNC_COPY16(srcA + 64, &xs[1][2 * wave][0]);
    ASYNC_COPY16(srcB + 64, &xs[1][2 * wave + 1][0]);
    __builtin_amdgcn_sched_barrier(0);

    int bc = 0;   // buffer holding chunk c
    int bf = 2;   // buffer to fill with chunk c+2

#pragma unroll 1
    for (int c = 0; c < 32; ++c) {
        // -- 1. counted wait: chunk c's 2 DMAs retired (in-order counter).
        if (c == 0)       asm volatile("s_waitcnt vmcnt(2)" ::: "memory");
        else if (c == 31) asm volatile("s_waitcnt vmcnt(0)" ::: "memory");
        else              asm volatile("s_waitcnt vmcnt(8)" ::: "memory");
        __builtin_amdgcn_sched_barrier(0);
        __builtin_amdgcn_s_barrier();        // raw: no vmcnt(0) drain
        __builtin_amdgcn_sched_barrier(0);

        // -- 2. phi f16 loads for chunk c FIRST (before any new DMA) --
        const half4_t p0 = *pb0;
        const half4_t p1 = *pb1;
        const half4_t p2 = *pb2;
        const half4_t p3 = *pb3;
        const half4_t p4 = *pb4;
        const half4_t p5 = *pb5;
        __builtin_amdgcn_sched_barrier(0);

        // -- 3. prefetch chunk c+2 into bf --
        if (c < 30) {
            ASYNC_COPY16(srcA + 128, &xs[bf][2 * wave][0]);
            ASYNC_COPY16(srcB + 128, &xs[bf][2 * wave + 1][0]);
        }
        __builtin_amdgcn_sched_barrier(0);

        // split phi half4 -> half2 pairs
        const half2_t p0l = __builtin_shufflevector(p0, p0, 0, 1);
        const half2_t p0h = __builtin_shufflevector(p0, p0, 2, 3);
        const half2_t p1l = __builtin_shufflevector(p1, p1, 0, 1);
        const half2_t p1h = __builtin_shufflevector(p1, p1, 2, 3);
        const half2_t p2l = __builtin_shufflevector(p2, p2, 0, 1);
        const half2_t p2h = __builtin_shufflevector(p2, p2, 2, 3);
        const half2_t p3l = __builtin_shufflevector(p3, p3, 0, 1);
        const half2_t p3h = __builtin_shufflevector(p3, p3, 2, 3);
        const half2_t p4l = __builtin_shufflevector(p4, p4, 0, 1);
        const half2_t p4h = __builtin_shufflevector(p4, p4, 2, 3);
        const half2_t p5l = __builtin_shufflevector(p5, p5, 0, 1);
        const half2_t p5h = __builtin_shufflevector(p5, p5, 2, 3);

        // -- 4. consume chunk c: 8 ds_read_b128 + cvt + 96 fdot2 --
#pragma unroll
        for (int r = 0; r < 8; ++r) {
            const float4 xv = xs[bc][r][lane];
            const half2_t xl = __builtin_amdgcn_cvt_pkrtz(xv.x, xv.y);
            const half2_t xh = __builtin_amdgcn_cvt_pkrtz(xv.z, xv.w);

            acc[r][0] = __builtin_amdgcn_fdot2(xl, p0l, acc[r][0], false);
            acc[r][0] = __builtin_amdgcn_fdot2(xh, p0h, acc[r][0], false);
            acc[r][1] = __builtin_amdgcn_fdot2(xl, p1l, acc[r][1], false);
            acc[r][1] = __builtin_amdgcn_fdot2(xh, p1h, acc[r][1], false);
            acc[r][2] = __builtin_amdgcn_fdot2(xl, p2l, acc[r][2], false);
            acc[r][2] = __builtin_amdgcn_fdot2(xh, p2h, acc[r][2], false);
            acc[r][3] = __builtin_amdgcn_fdot2(xl, p3l, acc[r][3], false);
            acc[r][3] = __builtin_amdgcn_fdot2(xh, p3h, acc[r][3], false);
            acc[r][4] = __builtin_amdgcn_fdot2(xl, p4l, acc[r][4], false);
            acc[r][4] = __builtin_amdgcn_fdot2(xh, p4h, acc[r][4], false);
            acc[r][5] = __builtin_amdgcn_fdot2(xl, p5l, acc[r][5], false);
            acc[r][5] = __builtin_amdgcn_fdot2(xh, p5h, acc[r][5], false);

            // ssq of this wave's own rows, f32 (wave-uniform scalar branch)
            if (r == wr0)      DOT4(ssq0, xv, xv)
            else if (r == wr1) DOT4(ssq1, xv, xv)
        }

        // advance
        srcA += 64; srcB += 64;
        pb0 += 64; pb1 += 64; pb2 += 64; pb3 += 64; pb4 += 64; pb5 += 64;
        bc = (bc == 2) ? 0 : bc + 1;
        bf = (bf == 2) ? 0 : bf + 1;
    }

    // butterfly reduce across all 64 lanes (lanes cover distinct K positions)
#pragma unroll
    for (int r = 0; r < 8; ++r)
#pragma unroll
        for (int j = 0; j < 6; ++j) {
            float v = acc[r][j];
#pragma unroll
            for (int off = 32; off > 0; off >>= 1)
                v += __shfl_xor(v, off, 64);
            acc[r][j] = v;
        }
#pragma unroll
    for (int off = 32; off > 0; off >>= 1)
        ssq0 += __shfl_xor(ssq0, off, 64);
#pragma unroll
    for (int off = 32; off > 0; off >>= 1)
        ssq1 += __shfl_xor(ssq1, off, 64);

    if (lane == 0) {
#pragma unroll
        for (int r = 0; r < 8; ++r)
#pragma unroll
            for (int j = 0; j < 6; ++j)
                red[wave][r][j] = acc[r][j];
        redss[2 * wave]     = ssq0;
        redss[2 * wave + 1] = ssq1;
    }
    __syncthreads();

    // final gather; 200 threads -> dots_part[kb][8 rows][25]
    const int t = threadIdx.x;
    if (t < 200) {
        const int r = t / 25, o = t % 25;
        float s;
        if (o < 24) s = red[o / 6][r][o % 6];   // phi row o handled by wave o/6
        else        s = redss[r];               // ssq of row r
        dots_part[((size_t)kb * B_ROWS + (b0 + r)) * 25 + o] = s;
    }
}

// ---------------------------------------------------------------------------
// Kernel 2: per-row finalize: sum K-halves, rms factor, softmax, 2*sigmoid,
// Sinkhorn(20).
// dots layout: [0..3]=pre, [4..7]=post, [8..23]=res, [24]=ssq
// params layout: [0..3]=H_pre, [4..7]=H_post, [8..23]=M (row-major 4x4)
// ---------------------------------------------------------------------------
__global__ void finalize_kernel(
    const float* __restrict__ dots_part,
    const float* __restrict__ b_pre,
    const float* __restrict__ b_post,
    const float* __restrict__ b_res,
    const float* __restrict__ alpha_pre,
    const float* __restrict__ alpha_post,
    const float* __restrict__ alpha_res,
    float* __restrict__ params)
{
    const int row = blockIdx.x * blockDim.x + threadIdx.x;
    if (row >= B_ROWS) return;

    const float* d0 = dots_part + (size_t)row * 25;
    const float* d1 = dots_part + ((size_t)B_ROWS + row) * 25;
    float d[25];
#pragma unroll
    for (int o = 0; o < 25; ++o) d[o] = d0[o] + d1[o];

    const float inv_rms = rsqrtf(d[24] * (1.f / (float)NC) + 1e-8f);
    const float ap  = alpha_pre[0];
    const float apo = alpha_post[0];
    const float ar  = alpha_res[0];

    // softmax(h_pre)
    float hp[4];
    float mx = -1e30f;
#pragma unroll
    for (int j = 0; j < 4; ++j) {
        hp[j] = ap * d[j] * inv_rms + b_pre[j];
        mx = fmaxf(mx, hp[j]);
    }
    float e[4], s = 0.f;
#pragma unroll
    for (int j = 0; j < 4; ++j) { e[j] = expf(hp[j] - mx); s += e[j]; }
    float Hpre[4];
#pragma unroll
    for (int j = 0; j < 4; ++j) Hpre[j] = e[j] / s;

    // 2*sigmoid(h_post)
    float Hpost[4];
#pragma unroll
    for (int j = 0; j < 4; ++j) {
        const float h = apo * d[4 + j] * inv_rms + b_post[j];
        Hpost[j] = 2.f / (1.f + expf(-h));
    }

    // Sinkhorn on exp(h_res)
    float M[16];
#pragma unroll
    for (int k = 0; k < 16; ++k)
        M[k] = expf(ar * d[8 + k] * inv_rms + b_res[k]);

    for (int it = 0; it < 20; ++it) {
#pragma unroll
        for (int i = 0; i < 4; ++i) {
            const float rs = M[i*4+0] + M[i*4+1] + M[i*4+2] + M[i*4+3] + 1e-8f;
#pragma unroll
            for (int j = 0; j < 4; ++j) M[i*4+j] = M[i*4+j] / rs;
        }
#pragma unroll
        for (int j = 0; j < 4; ++j) {
            const float cs = M[0*4+j] + M[1*4+j] + M[2*4+j] + M[3*4+j] + 1e-8f;
#pragma unroll
            for (int i = 0; i < 4; ++i) M[i*4+j] = M[i*4+j] / cs;
        }
    }

    float* p = params + (size_t)row * 24;
#pragma unroll
    for (int j = 0; j < 4; ++j)  p[j]     = Hpre[j];
#pragma unroll
    for (int j = 0; j < 4; ++j)  p[4 + j] = Hpost[j];
#pragma unroll
    for (int k = 0; k < 16; ++k) p[8 + k] = M[k];
}

// ---------------------------------------------------------------------------
// Kernel 3: output. One block per batch row; x row held in registers
// (64 floats/thread), block-reduced RMS of x_agg, then fused epilogue.
// ---------------------------------------------------------------------------
__global__ __launch_bounds__(256, 2) void out_kernel(
    const float* __restrict__ x,
    const float* __restrict__ w,
    const float* __restrict__ params,
    float* __restrict__ out)
{
    const float4* __restrict__ x4 = reinterpret_cast<const float4*>(x);
    const float4* __restrict__ w4 = reinterpret_cast<const float4*>(w);
    float4* __restrict__ out4 = reinterpret_cast<float4*>(out);

    const int b = blockIdx.x;
    const float* __restrict__ p = params + (size_t)b * 24;

    float Hpre[4], Hpost[4], M[16];
#pragma unroll
    for (int j = 0; j < 4; ++j)  Hpre[j]  = p[j];
#pragma unroll
    for (int j = 0; j < 4; ++j)  Hpost[j] = p[4 + j];
#pragma unroll
    for (int k = 0; k < 16; ++k) M[k]     = p[8 + k];

    const int t = threadIdx.x;
    const size_t base = (size_t)b * NC4;

    float4 xv[4][4];
    float4 agg[4];
    float ssq = 0.f;

#pragma unroll
    for (int u = 0; u < 4; ++u) {
        const int c4 = u * 256 + t;
#pragma unroll
        for (int n = 0; n < 4; ++n)
            xv[u][n] = x4[base + (size_t)n * C4 + c4];

        float4 a;
        a.x = Hpre[0]*xv[u][0].x + Hpre[1]*xv[u][1].x + Hpre[2]*xv[u][2].x + Hpre[3]*xv[u][3].x;
        a.y = Hpre[0]*xv[u][0].y + Hpre[1]*xv[u][1].y + Hpre[2]*xv[u][2].y + Hpre[3]*xv[u][3].y;
        a.z = Hpre[0]*xv[u][0].z + Hpre[1]*xv[u][1].z + Hpre[2]*xv[u][2].z + Hpre[3]*xv[u][3].z;
        a.w = Hpre[0]*xv[u][0].w + Hpre[1]*xv[u][1].w + Hpre[2]*xv[u][2].w + Hpre[3]*xv[u][3].w;
        agg[u] = a;
        ssq += a.x*a.x + a.y*a.y + a.z*a.z + a.w*a.w;
    }

#pragma unroll
    for (int off = 32; off > 0; off >>= 1)
        ssq += __shfl_xor(ssq, off, 64);
    __shared__ float red[4];
    if ((t & 63) == 0) red[t >> 6] = ssq;
    __syncthreads();
    const float total = red[0] + red[1] + red[2] + red[3];
    const float inv = rsqrtf(total * (1.f / (float)C_DIM) + 1e-5f);

#pragma unroll
    for (int u = 0; u < 4; ++u) {
        const int c4 = u * 256 + t;
        const float4 wv = w4[c4];
        float4 y;
        y.x = agg[u].x * inv * wv.x;
        y.y = agg[u].y * inv * wv.y;
        y.z = agg[u].z * inv * wv.z;
        y.w = agg[u].w * inv * wv.w;

#pragma unroll
        for (int i = 0; i < 4; ++i) {
            float4 o;
            o.x = Hpost[i]*y.x + M[i*4+0]*xv[u][0].x + M[i*4+1]*xv[u][1].x
                               + M[i*4+2]*xv[u][2].x + M[i*4+3]*xv[u][3].x;
            o.y = Hpost[i]*y.y + M[i*4+0]*xv[u][0].y + M[i*4+1]*xv[u][1].y
                               + M[i*4+2]*xv[u][2].y + M[i*4+3]*xv[u][3].y;
            o.z = Hpost[i]*y.z + M[i*4+0]*xv[u][0].z + M[i*4+1]*xv[u][1].z
                               + M[i*4+2]*xv[u][2].z + M[i*4+3]*xv[u][3].z;
            o.w = Hpost[i]*y.w + M[i*4+0]*xv[u][0].w + M[i*4+1]*xv[u][1].w
                               + M[i*4+2]*xv[u][2].w + M[i*4+3]*xv[u][3].w;
            out4[base + (size_t)i * C4 + c4] = o;
        }
    }
}

// ---------------------------------------------------------------------------
extern "C" void kernel_launch(void* const* d_in, const int* in_sizes, int n_in,
                              void* d_out, int out_size, void* d_ws, size_t ws_size,
                              hipStream_t stream) {
    const float* x        = (const float*)d_in[0];
    const float* w        = (const float*)d_in[1];
    const float* phi_pre  = (const float*)d_in[2];
    const float* phi_post = (const float*)d_in[3];
    const float* phi_res  = (const float*)d_in[4];
    const float* b_pre    = (const float*)d_in[5];
    const float* b_post   = (const float*)d_in[6];
    const float* b_res    = (const float*)d_in[7];
    const float* a_pre    = (const float*)d_in[8];
    const float* a_post   = (const float*)d_in[9];
    const float* a_res    = (const float*)d_in[10];
    float* out = (float*)d_out;

    float*   dots_part = (float*)d_ws;                          // [2][4096][25]
    float*   params    = dots_part + (size_t)2 * B_ROWS * 25;   // [4096][24]
    half4_t* phi16     = (half4_t*)(params + (size_t)B_ROWS * 24); // [24][4096]

    hipLaunchKernelGGL(repack16_kernel, dim3((24 * NC4 + 255) / 256), dim3(256), 0, stream,
                       (const float4*)phi_pre, (const float4*)phi_post,
                       (const float4*)phi_res, phi16);
    hipLaunchKernelGGL(proj_kernel, dim3(B_ROWS / 4), dim3(256), 0, stream,
                       x, phi16, dots_part);
    hipLaunchKernelGGL(finalize_kernel, dim3(B_ROWS / 256), dim3(256), 0, stream,
                       dots_part, b_pre, b_post, b_res, a_pre, a_post, a_res, params);
    hipLaunchKernelGGL(out_kernel, dim3(B_ROWS), dim3(256), 0, stream,
                       x, w, params, out);
}